// Round 14
// baseline (146.064 us; speedup 1.0000x reference)
//
#include <hip/hip_runtime.h>
#include <hip/hip_bf16.h>

// Problem constants (B=2, T=2048, D=768, E=8, H=1536, K=2)
#define NTOK 4096
#define DDIM 768
#define EEXP 8
#define HDIM 1536
#define MBLK 128
#define MAXMB 72            // sum ceil(cnt_e/128) <= 64+7, +margin
#define CAP  (MAXMB * MBLK) // 9216
#define NENT (NTOK * 2)     // 8192 routed (token,k) entries
#define RTHREADS 1024
#define EPT (NENT / RTHREADS) // 8 entries per route thread
#define NGATE (NTOK / 4)      // 1024 gating blocks
#define NTTILE 6912           // transpose tiles: 24 z-banks * 288

typedef float f32x4 __attribute__((ext_vector_type(4)));
typedef __bf16 bf16x8 __attribute__((ext_vector_type(8)));
typedef __bf16 bf16x4 __attribute__((ext_vector_type(4)));

// ---------------- workspace layout (bytes) ----------------
static const size_t XB_OFF   = 0;                       // bf16 x [NTOK][D]      6,291,456
static const size_t GT_OFF   = 6291456;                 // bf16 Gt [E][H][D]    18,874,368
static const size_t UT_OFF   = GT_OFF + 18874368;       // bf16 Ut [E][H][D]    18,874,368
static const size_t YB_OFF   = GT_OFF;                  // bf16 ybuf [CAP][D]   14,155,776 (aliases Gt, dead after gateup)
static const size_t DT_OFF   = UT_OFF + 18874368;       // bf16 Dt [E][D][H]    18,874,368
static const size_t HB_OFF   = DT_OFF + 18874368;       // bf16 h  [CAP][H]     28,311,552
static const size_t TKI_OFF  = HB_OFF + 28311552;       // int  topk_idx [NENT]
static const size_t TKW_OFF  = TKI_OFF + NENT*4;        // f32  topk_w   [NENT]
static const size_t PT_OFF   = TKW_OFF + NENT*4;        // int  pair_token [CAP]
static const size_t SL_OFF   = PT_OFF + CAP*4;          // int  slot_of  [NENT]
static const size_t CTRL_OFF = SL_OFF + NENT*4;
static const size_t WS_NEEDED = CTRL_OFF + 1024;

#define GLOAD16(g, l) __builtin_amdgcn_global_load_lds( \
    (const __attribute__((address_space(1))) void*)(g),  \
    (__attribute__((address_space(3))) void*)(l), 16, 0, 0)

#define MFMA_BF16 __builtin_amdgcn_mfma_f32_16x16x32_bf16

// T2 swizzle (16x16 fragments, BK=64 rows = 128 B = 8 x 16B units; VERIFIED
// conflict-free r8/r9/r11): stored unit = src_unit ^ (row&7); read addr =
// row*64 + (kb ^ ((row&7)<<3)). Staging pre-swizzles the GLOBAL source
// column; LDS write stays linear (global_load_lds constraint).
// (REGRESSED variants — do not reintroduce: BK=32 [r12], 32x32 fragments
// [r10], 256-wide down tile with <1 block/CU [r13].)

// ---------------- prep: gating + x-convert + all weight transposes, ONE launch ----
__global__ __launch_bounds__(256) void prep_kernel(
    const float* __restrict__ x, const float* __restrict__ gw,
    int* __restrict__ topk_idx, float* __restrict__ topk_w,
    __bf16* __restrict__ xb,
    const float* __restrict__ gb, const float* __restrict__ ub,
    const float* __restrict__ db, __bf16* __restrict__ Gt,
    __bf16* __restrict__ Ut, __bf16* __restrict__ Dt)
{
    __shared__ float tile[64][65];
    int tid = threadIdx.x;

    if (blockIdx.x < NGATE) {
        // ---- gating + fused bf16 convert ----
        int lane = tid & 63;
        int t = blockIdx.x * 4 + (tid >> 6);
        const float* xr = x + (size_t)t * DDIM;
        __bf16* xbr = xb + (size_t)t * DDIM;
        float acc[EEXP];
#pragma unroll
        for (int e = 0; e < EEXP; e++) acc[e] = 0.0f;
#pragma unroll
        for (int i = 0; i < DDIM / 64; i++) {
            int d = lane + i * 64;
            float xv = xr[d];
            xbr[d] = (__bf16)xv;
#pragma unroll
            for (int e = 0; e < EEXP; e++) acc[e] += xv * gw[e * DDIM + d];
        }
#pragma unroll
        for (int e = 0; e < EEXP; e++) {
            for (int off = 32; off; off >>= 1) acc[e] += __shfl_xor(acc[e], off);
        }
        if (lane == 0) {
            float m = acc[0];
#pragma unroll
            for (int e = 1; e < EEXP; e++) m = fmaxf(m, acc[e]);
            float p[EEXP], sum = 0.0f;
#pragma unroll
            for (int e = 0; e < EEXP; e++) { p[e] = expf(acc[e] - m); sum += p[e]; }
            int i0 = 0; float b0 = acc[0];
#pragma unroll
            for (int e = 1; e < EEXP; e++) if (acc[e] > b0) { b0 = acc[e]; i0 = e; }
            int i1 = -1; float b1 = -3.4e38f;
#pragma unroll
            for (int e = 0; e < EEXP; e++) if (e != i0 && acc[e] > b1) { b1 = acc[e]; i1 = e; }
            float pr0 = p[i0] / sum, pr1 = p[i1] / sum;
            float den = pr0 + pr1 + 1e-8f;
            topk_idx[2*t]   = i0; topk_w[2*t]   = pr0 / den;
            topk_idx[2*t+1] = i1; topk_w[2*t+1] = pr1 / den;
        }
        return;
    }

    // ---- 64x64 transpose+convert tile ----
    int bt = blockIdx.x - NGATE;      // 0..6911
    int z = bt / 288, rem = bt - z * 288;
    int bank = z >> 3, e = z & 7;
    int R, C, r0, c0;
    const float* s;
    __bf16* d;
    if (bank < 2) {
        R = DDIM; C = HDIM;
        s = (bank == 0 ? gb : ub) + (size_t)e * DDIM * HDIM;
        d = (bank == 0 ? Gt : Ut) + (size_t)e * DDIM * HDIM;
        c0 = (rem % 24) * 64; r0 = (rem / 24) * 64;
    } else {
        R = HDIM; C = DDIM;
        s = db + (size_t)e * DDIM * HDIM;
        d = Dt + (size_t)e * DDIM * HDIM;
        r0 = (rem % 24) * 64; c0 = (rem / 24) * 64;
    }
    int tx = tid & 15, ty = tid >> 4;   // 16 x 16
#pragma unroll
    for (int j = 0; j < 4; j++) {
        int r = ty + j * 16;
        f32x4 v = *reinterpret_cast<const f32x4*>(&s[(size_t)(r0 + r) * C + c0 + tx * 4]);
        tile[r][tx*4+0] = v[0]; tile[r][tx*4+1] = v[1];
        tile[r][tx*4+2] = v[2]; tile[r][tx*4+3] = v[3];
    }
    __syncthreads();
#pragma unroll
    for (int j = 0; j < 4; j++) {
        int c = ty + j * 16;
        bf16x4 o;
#pragma unroll
        for (int i = 0; i < 4; i++) o[i] = (__bf16)tile[tx*4+i][c];
        *reinterpret_cast<bf16x4*>(&d[(size_t)(c0 + c) * R + r0 + tx*4]) = o;
    }
}

// ---------------- routing: single-block deterministic, no atomics ----------------
__global__ __launch_bounds__(RTHREADS) void route_kernel(
    const int* __restrict__ topk_idx, int* __restrict__ ctrl,
    int* __restrict__ pair_token, int* __restrict__ slot_of)
{
    __shared__ int wt[EEXP][16];
    __shared__ int wpre[EEXP][16];
    __shared__ int base[EEXP];

    int tid = threadIdx.x;
    int lane = tid & 63, wv = tid >> 6;

    for (int i = tid; i < CAP; i += RTHREADS) pair_token[i] = 0;

    int e_of[EPT];
    int c[EEXP];
#pragma unroll
    for (int e = 0; e < EEXP; e++) c[e] = 0;
#pragma unroll
    for (int j = 0; j < EPT; j++) {
        int e = topk_idx[tid * EPT + j];
        e_of[j] = e;
        c[e]++;
    }
    int pre[EEXP];
#pragma unroll
    for (int e = 0; e < EEXP; e++) {
        int v = c[e];
        for (int d = 1; d < 64; d <<= 1) {
            int u = __shfl_up(v, d);
            if (lane >= d) v += u;
        }
        pre[e] = v - c[e];
        if (lane == 63) wt[e][wv] = v;
    }
    __syncthreads();
    if (tid == 0) {
        int off = 0, gmb = 0;
        for (int e = 0; e < EEXP; e++) {
            int run = 0;
            for (int w = 0; w < 16; w++) { wpre[e][w] = run; run += wt[e][w]; }
            base[e] = off;
            int nmb = (run + MBLK - 1) >> 7;
            for (int i = 0; i < nmb; i++) ctrl[32 + gmb++] = e;
            off += nmb << 7;
        }
        ctrl[24] = gmb;
    }
    __syncthreads();
    int run[EEXP];
#pragma unroll
    for (int e = 0; e < EEXP; e++) run[e] = base[e] + wpre[e][wv] + pre[e];
#pragma unroll
    for (int j = 0; j < EPT; j++) {
        int ent = tid * EPT + j;
        int e = e_of[j];
        int slot = run[e]++;
        pair_token[slot] = ent >> 1;
        slot_of[ent] = slot;
    }
}

// ------- gate/up fused GEMM: persistent 2-tile blocks, zero grid tail -------
// 432 blocks (all co-resident at 3/CU: 432 < 768), each does TWO adjacent
// 128x128 column panels (y = 2p, 2p+1) of one mblock -> uniform block length,
// no 96-block straggler tail (was 864 blocks vs 768 slots = ~12% tail).
// Inner: r9/r11 verified config — BK=64, 12 unrolled steps, 4 waves (2x2),
// 64x64 wave tiles, T2 swizzle, 0 bank conflicts.
__global__ __launch_bounds__(256, 2) void gateup_kernel(
    const __bf16* __restrict__ xb, const __bf16* __restrict__ Gt,
    const __bf16* __restrict__ Ut, const int* __restrict__ ctrl,
    const int* __restrict__ pair_token, __bf16* __restrict__ hbuf)
{
    // flattened grid, pair-fastest; bijective XCD chunk swizzle (432 % 8 == 0)
    int bid = blockIdx.x;
    int swz = (bid & 7) * (MAXMB * 6 / 8) + (bid >> 3);
    int mb = swz / 6, ypair = swz - mb * 6;
    if (mb >= ctrl[24]) return;
    int e = ctrl[32 + mb];
    const __bf16* G = Gt + (size_t)e * HDIM * DDIM;   // [H][D]
    const __bf16* U = Ut + (size_t)e * HDIM * DDIM;

    __shared__ __bf16 lds[3 * 8192];   // 48 KB: A | Bg | Bu, each [128][64]

    int tid = threadIdx.x;
    int lane = tid & 63, w = tid >> 6;
    int wr = w >> 1, wc = w & 1;

    // staging: one GLOAD16 x 256 thr = 4 KB = 32 rows x 128 B.
    int lr = tid >> 3;                        // row in 32-row chunk
    int lc = ((tid & 7) ^ (lr & 7)) << 3;     // pre-swizzled source col elem
    const __bf16* gA[4];
#pragma unroll
    for (int j = 0; j < 4; j++) {
        int tok = pair_token[mb * MBLK + j * 32 + lr];
        gA[j] = xb + (size_t)tok * DDIM + lc;
    }
    const size_t rstep = (size_t)32 * DDIM;
    size_t slotbase = (size_t)mb * MBLK;

#pragma unroll
    for (int rep = 0; rep < 2; rep++) {
        int hbase = (ypair * 2 + rep) * 128;
        const __bf16* gG = G + (size_t)(hbase + lr) * DDIM + lc;   // + j*32 rows
        const __bf16* gU = U + (size_t)(hbase + lr) * DDIM + lc;

        f32x4 accg[4][4], accu[4][4];
#pragma unroll
        for (int m = 0; m < 4; m++)
#pragma unroll
            for (int n = 0; n < 4; n++) { accg[m][n] = (f32x4)0.0f; accu[m][n] = (f32x4)0.0f; }

#pragma unroll
        for (int kt = 0; kt < DDIM / 64; kt++) {
            const int kk = kt * 64;
#pragma unroll
            for (int j = 0; j < 4; j++)
                GLOAD16(gA[j] + kk, &lds[j * 2048 + tid * 8]);
#pragma unroll
            for (int j = 0; j < 4; j++)
                GLOAD16(gG + kk + j * rstep, &lds[8192 + j * 2048 + tid * 8]);
#pragma unroll
            for (int j = 0; j < 4; j++)
                GLOAD16(gU + kk + j * rstep, &lds[16384 + j * 2048 + tid * 8]);
            __syncthreads();

#pragma unroll
            for (int ks = 0; ks < 2; ks++) {
                int kb = ks * 32 + (lane >> 4) * 8;
                bf16x8 af[4], bg[4], bu[4];
#pragma unroll
                for (int m = 0; m < 4; m++) {
                    int row = wr * 64 + m * 16 + (lane & 15);
                    af[m] = *reinterpret_cast<const bf16x8*>(
                        &lds[row * 64 + (kb ^ ((row & 7) << 3))]);
                }
#pragma unroll
                for (int n = 0; n < 4; n++) {
                    int col = wc * 64 + n * 16 + (lane & 15);
                    int ba = col * 64 + (kb ^ ((col & 7) << 3));
                    bg[n] = *reinterpret_cast<const bf16x8*>(&lds[8192 + ba]);
                    bu[n] = *reinterpret_cast<const bf16x8*>(&lds[16384 + ba]);
                }
#pragma unroll
                for (int n = 0; n < 4; n++)
#pragma unroll
                    for (int m = 0; m < 4; m++) {
                        accg[m][n] = MFMA_BF16(af[m], bg[n], accg[m][n], 0, 0, 0);
                        accu[m][n] = MFMA_BF16(af[m], bu[n], accu[m][n], 0, 0, 0);
                    }
            }
            __syncthreads();   // also protects LDS before next rep's staging
        }

#pragma unroll
        for (int m = 0; m < 4; m++)
#pragma unroll
            for (int n = 0; n < 4; n++)
#pragma unroll
                for (int r = 0; r < 4; r++) {
                    int row = wr * 64 + m * 16 + (lane >> 4) * 4 + r;
                    int col = hbase + wc * 64 + n * 16 + (lane & 15);
                    float a = accg[m][n][r], u = accu[m][n][r];
                    float hv = (a / (1.0f + expf(-a))) * u;
                    hbuf[(slotbase + row) * HDIM + col] = (__bf16)hv;
                }
    }
}

// ------- down GEMM: m97 structure, BK=64, 64x64 wave tiles + T2 swizzle -------
// (r11 verified config) Tile 128x128, K=1536 (24 steps unrolled). LDS 32 KB;
// 432 blocks at >=3/CU: all co-resident, cross-block drain hiding active.
__global__ __launch_bounds__(256, 3) void down_kernel(
    const __bf16* __restrict__ hbuf, const __bf16* __restrict__ Dt,
    const int* __restrict__ ctrl, __bf16* __restrict__ ybuf)
{
    int bid = blockIdx.x;
    int swz = (bid & 7) * (MAXMB * 6 / 8) + (bid >> 3);   // 432 % 8 == 0
    int mb = swz / 6, y = swz - mb * 6;
    if (mb >= ctrl[24]) return;
    int e = ctrl[32 + mb];
    int dbase = y * 128;
    const __bf16* Dn = Dt + (size_t)e * DDIM * HDIM;   // [D][H]

    __shared__ __bf16 lds[2 * 8192];   // 32 KB: A | B

    int tid = threadIdx.x;
    int lane = tid & 63, w = tid >> 6;
    int wr = w >> 1, wc = w & 1;

    int lr = tid >> 3;
    int lc = ((tid & 7) ^ (lr & 7)) << 3;
    const __bf16* gA = hbuf + (size_t)(mb * MBLK + lr) * HDIM + lc;   // + j*32 rows
    const __bf16* gB = Dn + (size_t)(dbase + lr) * HDIM + lc;
    const size_t rstep = (size_t)32 * HDIM;

    f32x4 acc[4][4];
#pragma unroll
    for (int m = 0; m < 4; m++)
#pragma unroll
        for (int n = 0; n < 4; n++) acc[m][n] = (f32x4)0.0f;

#pragma unroll
    for (int kt = 0; kt < HDIM / 64; kt++) {
        const int kk = kt * 64;
#pragma unroll
        for (int j = 0; j < 4; j++)
            GLOAD16(gA + kk + j * rstep, &lds[j * 2048 + tid * 8]);
#pragma unroll
        for (int j = 0; j < 4; j++)
            GLOAD16(gB + kk + j * rstep, &lds[8192 + j * 2048 + tid * 8]);
        __syncthreads();

#pragma unroll
        for (int ks = 0; ks < 2; ks++) {
            int kb = ks * 32 + (lane >> 4) * 8;
            bf16x8 af[4], bd[4];
#pragma unroll
            for (int m = 0; m < 4; m++) {
                int row = wr * 64 + m * 16 + (lane & 15);
                af[m] = *reinterpret_cast<const bf16x8*>(
                    &lds[row * 64 + (kb ^ ((row & 7) << 3))]);
            }
#pragma unroll
            for (int n = 0; n < 4; n++) {
                int col = wc * 64 + n * 16 + (lane & 15);
                bd[n] = *reinterpret_cast<const bf16x8*>(
                    &lds[8192 + col * 64 + (kb ^ ((col & 7) << 3))]);
            }
#pragma unroll
            for (int n = 0; n < 4; n++)
#pragma unroll
                for (int m = 0; m < 4; m++)
                    acc[m][n] = MFMA_BF16(af[m], bd[n], acc[m][n], 0, 0, 0);
        }
        __syncthreads();
    }

#pragma unroll
    for (int m = 0; m < 4; m++)
#pragma unroll
        for (int n = 0; n < 4; n++)
#pragma unroll
            for (int r = 0; r < 4; r++) {
                int row = wr * 64 + m * 16 + (lane >> 4) * 4 + r;
                int col = dbase + wc * 64 + n * 16 + (lane & 15);
                ybuf[(size_t)(mb * MBLK + row) * DDIM + col] = (__bf16)acc[m][n][r];
            }
}

// combine: out[t] = w0*y[s0] + w1*y[s1] (bf16 y, f32 math); overwrites d_out.
__global__ __launch_bounds__(192) void combine_kernel(
    const __bf16* __restrict__ ybuf, const int* __restrict__ slot_of,
    const float* __restrict__ topk_w, float* __restrict__ out)
{
    int t = blockIdx.x;
    int q = threadIdx.x;
    int s0 = slot_of[2*t], s1 = slot_of[2*t+1];
    float w0 = topk_w[2*t], w1 = topk_w[2*t+1];
    bf16x4 y0 = reinterpret_cast<const bf16x4*>(ybuf + (size_t)s0 * DDIM)[q];
    bf16x4 y1 = reinterpret_cast<const bf16x4*>(ybuf + (size_t)s1 * DDIM)[q];
    f32x4 o;
#pragma unroll
    for (int r = 0; r < 4; r++) o[r] = w0 * (float)y0[r] + w1 * (float)y1[r];
    reinterpret_cast<f32x4*>(out + (size_t)t * DDIM)[q] = o;
}

// ---------------- launch ----------------
extern "C" void kernel_launch(void* const* d_in, const int* in_sizes, int n_in,
                              void* d_out, int out_size, void* d_ws, size_t ws_size,
                              hipStream_t stream)
{
    if (ws_size < WS_NEEDED) return;

    const float* x      = (const float*)d_in[0];
    const float* gate_w = (const float*)d_in[1];
    const float* gbank  = (const float*)d_in[2];
    const float* ubank  = (const float*)d_in[3];
    const float* dbank  = (const float*)d_in[4];
    float* out = (float*)d_out;

    char* ws = (char*)d_ws;
    __bf16* xb   = (__bf16*)(ws + XB_OFF);
    __bf16* Gt   = (__bf16*)(ws + GT_OFF);
    __bf16* Ut   = (__bf16*)(ws + UT_OFF);
    __bf16* ybuf = (__bf16*)(ws + YB_OFF);
    __bf16* Dt   = (__bf16*)(ws + DT_OFF);
    __bf16* hbuf = (__bf16*)(ws + HB_OFF);
    int*    tki  = (int*)(ws + TKI_OFF);
    float*  tkw  = (float*)(ws + TKW_OFF);
    int*    pt   = (int*)(ws + PT_OFF);
    int*    slot = (int*)(ws + SL_OFF);
    int*    ctrl = (int*)(ws + CTRL_OFF);

    prep_kernel<<<NGATE + NTTILE, 256, 0, stream>>>(
        x, gate_w, tki, tkw, xb, gbank, ubank, dbank, Gt, Ut, Dt);
    route_kernel<<<1, RTHREADS, 0, stream>>>(tki, ctrl, pt, slot);

    gateup_kernel<<<MAXMB * 6, 256, 0, stream>>>(xb, Gt, Ut, ctrl, pt, hbuf);
    down_kernel<<<MAXMB * 6, 256, 0, stream>>>(hbuf, Dt, ctrl, ybuf);
    combine_kernel<<<NTOK, 192, 0, stream>>>(ybuf, slot, tkw, out);
}

// Round 15
// 127.099 us; speedup vs baseline: 1.1492x; 1.1492x over previous
//
#include <hip/hip_runtime.h>
#include <hip/hip_bf16.h>

// Problem constants (B=2, T=2048, D=768, E=8, H=1536, K=2)
#define NTOK 4096
#define DDIM 768
#define EEXP 8
#define HDIM 1536
#define MBLK 128
#define MAXMB 72            // sum ceil(cnt_e/128) <= 64+7, +margin
#define CAP  (MAXMB * MBLK) // 9216
#define NENT (NTOK * 2)     // 8192 routed (token,k) entries
#define RTHREADS 1024
#define EPT (NENT / RTHREADS) // 8 entries per route thread
#define NGATE (NTOK / 4)      // 1024 gating blocks
#define NTTILE 6912           // transpose tiles: 24 z-banks * 288

typedef float f32x4 __attribute__((ext_vector_type(4)));
typedef __bf16 bf16x8 __attribute__((ext_vector_type(8)));
typedef __bf16 bf16x4 __attribute__((ext_vector_type(4)));

// ---------------- workspace layout (bytes) ----------------
static const size_t XB_OFF   = 0;                       // bf16 x [NTOK][D]      6,291,456
static const size_t GT_OFF   = 6291456;                 // bf16 Gt [E][H][D]    18,874,368
static const size_t UT_OFF   = GT_OFF + 18874368;       // bf16 Ut [E][H][D]    18,874,368
static const size_t YB_OFF   = GT_OFF;                  // bf16 ybuf [CAP][D]   14,155,776 (aliases Gt, dead after gateup)
static const size_t DT_OFF   = UT_OFF + 18874368;       // bf16 Dt [E][D][H]    18,874,368
static const size_t HB_OFF   = DT_OFF + 18874368;       // bf16 h  [CAP][H]     28,311,552
static const size_t TKI_OFF  = HB_OFF + 28311552;       // int  topk_idx [NENT]
static const size_t TKW_OFF  = TKI_OFF + NENT*4;        // f32  topk_w   [NENT]
static const size_t PT_OFF   = TKW_OFF + NENT*4;        // int  pair_token [CAP]
static const size_t SL_OFF   = PT_OFF + CAP*4;          // int  slot_of  [NENT]
static const size_t CTRL_OFF = SL_OFF + NENT*4;
static const size_t WS_NEEDED = CTRL_OFF + 1024;

#define GLOAD16(g, l) __builtin_amdgcn_global_load_lds( \
    (const __attribute__((address_space(1))) void*)(g),  \
    (__attribute__((address_space(3))) void*)(l), 16, 0, 0)

#define MFMA_BF16 __builtin_amdgcn_mfma_f32_16x16x32_bf16

// T2 swizzle (16x16 fragments, BK=64 rows = 128 B = 8 x 16B units; VERIFIED
// conflict-free r8/r9/r11): stored unit = src_unit ^ (row&7); read addr =
// row*64 + (kb ^ ((row&7)<<3)). Staging pre-swizzles the GLOBAL source
// column; LDS write stays linear (global_load_lds constraint).
// (REGRESSED variants — do not reintroduce: BK=32 [r12], 32x32 fragments
// [r10], 256-wide down tile [r13], persistent 2-tile gateup [r14].)

// ---------------- prep: gating + x-convert + all weight transposes, ONE launch ----
__global__ __launch_bounds__(256) void prep_kernel(
    const float* __restrict__ x, const float* __restrict__ gw,
    int* __restrict__ topk_idx, float* __restrict__ topk_w,
    __bf16* __restrict__ xb,
    const float* __restrict__ gb, const float* __restrict__ ub,
    const float* __restrict__ db, __bf16* __restrict__ Gt,
    __bf16* __restrict__ Ut, __bf16* __restrict__ Dt)
{
    __shared__ float tile[64][65];
    int tid = threadIdx.x;

    if (blockIdx.x < NGATE) {
        // ---- gating + fused bf16 convert ----
        int lane = tid & 63;
        int t = blockIdx.x * 4 + (tid >> 6);
        const float* xr = x + (size_t)t * DDIM;
        __bf16* xbr = xb + (size_t)t * DDIM;
        float acc[EEXP];
#pragma unroll
        for (int e = 0; e < EEXP; e++) acc[e] = 0.0f;
#pragma unroll
        for (int i = 0; i < DDIM / 64; i++) {
            int d = lane + i * 64;
            float xv = xr[d];
            xbr[d] = (__bf16)xv;
#pragma unroll
            for (int e = 0; e < EEXP; e++) acc[e] += xv * gw[e * DDIM + d];
        }
#pragma unroll
        for (int e = 0; e < EEXP; e++) {
            for (int off = 32; off; off >>= 1) acc[e] += __shfl_xor(acc[e], off);
        }
        if (lane == 0) {
            float m = acc[0];
#pragma unroll
            for (int e = 1; e < EEXP; e++) m = fmaxf(m, acc[e]);
            float p[EEXP], sum = 0.0f;
#pragma unroll
            for (int e = 0; e < EEXP; e++) { p[e] = expf(acc[e] - m); sum += p[e]; }
            int i0 = 0; float b0 = acc[0];
#pragma unroll
            for (int e = 1; e < EEXP; e++) if (acc[e] > b0) { b0 = acc[e]; i0 = e; }
            int i1 = -1; float b1 = -3.4e38f;
#pragma unroll
            for (int e = 0; e < EEXP; e++) if (e != i0 && acc[e] > b1) { b1 = acc[e]; i1 = e; }
            float pr0 = p[i0] / sum, pr1 = p[i1] / sum;
            float den = pr0 + pr1 + 1e-8f;
            topk_idx[2*t]   = i0; topk_w[2*t]   = pr0 / den;
            topk_idx[2*t+1] = i1; topk_w[2*t+1] = pr1 / den;
        }
        return;
    }

    // ---- 64x64 transpose+convert tile ----
    int bt = blockIdx.x - NGATE;      // 0..6911
    int z = bt / 288, rem = bt - z * 288;
    int bank = z >> 3, e = z & 7;
    int R, C, r0, c0;
    const float* s;
    __bf16* d;
    if (bank < 2) {
        R = DDIM; C = HDIM;
        s = (bank == 0 ? gb : ub) + (size_t)e * DDIM * HDIM;
        d = (bank == 0 ? Gt : Ut) + (size_t)e * DDIM * HDIM;
        c0 = (rem % 24) * 64; r0 = (rem / 24) * 64;
    } else {
        R = HDIM; C = DDIM;
        s = db + (size_t)e * DDIM * HDIM;
        d = Dt + (size_t)e * DDIM * HDIM;
        r0 = (rem % 24) * 64; c0 = (rem / 24) * 64;
    }
    int tx = tid & 15, ty = tid >> 4;   // 16 x 16
#pragma unroll
    for (int j = 0; j < 4; j++) {
        int r = ty + j * 16;
        f32x4 v = *reinterpret_cast<const f32x4*>(&s[(size_t)(r0 + r) * C + c0 + tx * 4]);
        tile[r][tx*4+0] = v[0]; tile[r][tx*4+1] = v[1];
        tile[r][tx*4+2] = v[2]; tile[r][tx*4+3] = v[3];
    }
    __syncthreads();
#pragma unroll
    for (int j = 0; j < 4; j++) {
        int c = ty + j * 16;
        bf16x4 o;
#pragma unroll
        for (int i = 0; i < 4; i++) o[i] = (__bf16)tile[tx*4+i][c];
        *reinterpret_cast<bf16x4*>(&d[(size_t)(c0 + c) * R + r0 + tx*4]) = o;
    }
}

// ---------------- routing: single-block deterministic, no atomics ----------------
__global__ __launch_bounds__(RTHREADS) void route_kernel(
    const int* __restrict__ topk_idx, int* __restrict__ ctrl,
    int* __restrict__ pair_token, int* __restrict__ slot_of)
{
    __shared__ int wt[EEXP][16];
    __shared__ int wpre[EEXP][16];
    __shared__ int base[EEXP];

    int tid = threadIdx.x;
    int lane = tid & 63, wv = tid >> 6;

    for (int i = tid; i < CAP; i += RTHREADS) pair_token[i] = 0;

    int e_of[EPT];
    int c[EEXP];
#pragma unroll
    for (int e = 0; e < EEXP; e++) c[e] = 0;
#pragma unroll
    for (int j = 0; j < EPT; j++) {
        int e = topk_idx[tid * EPT + j];
        e_of[j] = e;
        c[e]++;
    }
    int pre[EEXP];
#pragma unroll
    for (int e = 0; e < EEXP; e++) {
        int v = c[e];
        for (int d = 1; d < 64; d <<= 1) {
            int u = __shfl_up(v, d);
            if (lane >= d) v += u;
        }
        pre[e] = v - c[e];
        if (lane == 63) wt[e][wv] = v;
    }
    __syncthreads();
    if (tid == 0) {
        int off = 0, gmb = 0;
        for (int e = 0; e < EEXP; e++) {
            int run = 0;
            for (int w = 0; w < 16; w++) { wpre[e][w] = run; run += wt[e][w]; }
            base[e] = off;
            int nmb = (run + MBLK - 1) >> 7;
            for (int i = 0; i < nmb; i++) ctrl[32 + gmb++] = e;
            off += nmb << 7;
        }
        ctrl[24] = gmb;
    }
    __syncthreads();
    int run[EEXP];
#pragma unroll
    for (int e = 0; e < EEXP; e++) run[e] = base[e] + wpre[e][wv] + pre[e];
#pragma unroll
    for (int j = 0; j < EPT; j++) {
        int ent = tid * EPT + j;
        int e = e_of[j];
        int slot = run[e]++;
        pair_token[slot] = ent >> 1;
        slot_of[ent] = slot;
    }
}

// ------- gate/up fused GEMM: m97 structure, 64x64 wave tiles + T2 swizzle -------
// (r9/r11 configuration, verified best: ~58us, 0 bank conflicts, ~706 TF)
// Tile 128x128, BK=64, K=768 (12 steps, fully unrolled). 256 thr = 4 waves (2x2).
__global__ __launch_bounds__(256, 2) void gateup_kernel(
    const __bf16* __restrict__ xb, const __bf16* __restrict__ Gt,
    const __bf16* __restrict__ Ut, const int* __restrict__ ctrl,
    const int* __restrict__ pair_token, __bf16* __restrict__ hbuf)
{
    // flattened grid, y-fastest; bijective XCD chunk swizzle (864 % 8 == 0)
    int bid = blockIdx.x;
    int swz = (bid & 7) * (MAXMB * 12 / 8) + (bid >> 3);
    int mb = swz / 12, y = swz - mb * 12;
    if (mb >= ctrl[24]) return;
    int e = ctrl[32 + mb];
    int hbase = y * 128;
    const __bf16* G = Gt + (size_t)e * HDIM * DDIM;   // [H][D]
    const __bf16* U = Ut + (size_t)e * HDIM * DDIM;

    __shared__ __bf16 lds[3 * 8192];   // 48 KB: A | Bg | Bu, each [128][64]

    int tid = threadIdx.x;
    int lane = tid & 63, w = tid >> 6;
    int wr = w >> 1, wc = w & 1;

    // staging: one GLOAD16 x 256 thr = 4 KB = 32 rows x 128 B.
    int lr = tid >> 3;                        // row in 32-row chunk
    int lc = ((tid & 7) ^ (lr & 7)) << 3;     // pre-swizzled source col elem
    const __bf16* gA[4];
#pragma unroll
    for (int j = 0; j < 4; j++) {
        int tok = pair_token[mb * MBLK + j * 32 + lr];
        gA[j] = xb + (size_t)tok * DDIM + lc;
    }
    const __bf16* gG = G + (size_t)(hbase + lr) * DDIM + lc;   // + j*32 rows
    const __bf16* gU = U + (size_t)(hbase + lr) * DDIM + lc;
    const size_t rstep = (size_t)32 * DDIM;

    f32x4 accg[4][4], accu[4][4];
#pragma unroll
    for (int m = 0; m < 4; m++)
#pragma unroll
        for (int n = 0; n < 4; n++) { accg[m][n] = (f32x4)0.0f; accu[m][n] = (f32x4)0.0f; }

#pragma unroll
    for (int kt = 0; kt < DDIM / 64; kt++) {
        const int kk = kt * 64;
#pragma unroll
        for (int j = 0; j < 4; j++)
            GLOAD16(gA[j] + kk, &lds[j * 2048 + tid * 8]);
#pragma unroll
        for (int j = 0; j < 4; j++)
            GLOAD16(gG + kk + j * rstep, &lds[8192 + j * 2048 + tid * 8]);
#pragma unroll
        for (int j = 0; j < 4; j++)
            GLOAD16(gU + kk + j * rstep, &lds[16384 + j * 2048 + tid * 8]);
        __syncthreads();

#pragma unroll
        for (int ks = 0; ks < 2; ks++) {
            int kb = ks * 32 + (lane >> 4) * 8;
            bf16x8 af[4], bg[4], bu[4];
#pragma unroll
            for (int m = 0; m < 4; m++) {
                int row = wr * 64 + m * 16 + (lane & 15);
                af[m] = *reinterpret_cast<const bf16x8*>(
                    &lds[row * 64 + (kb ^ ((row & 7) << 3))]);
            }
#pragma unroll
            for (int n = 0; n < 4; n++) {
                int col = wc * 64 + n * 16 + (lane & 15);
                int ba = col * 64 + (kb ^ ((col & 7) << 3));
                bg[n] = *reinterpret_cast<const bf16x8*>(&lds[8192 + ba]);
                bu[n] = *reinterpret_cast<const bf16x8*>(&lds[16384 + ba]);
            }
#pragma unroll
            for (int n = 0; n < 4; n++)
#pragma unroll
                for (int m = 0; m < 4; m++) {
                    accg[m][n] = MFMA_BF16(af[m], bg[n], accg[m][n], 0, 0, 0);
                    accu[m][n] = MFMA_BF16(af[m], bu[n], accu[m][n], 0, 0, 0);
                }
        }
        __syncthreads();
    }

    size_t slotbase = (size_t)mb * MBLK;
#pragma unroll
    for (int m = 0; m < 4; m++)
#pragma unroll
        for (int n = 0; n < 4; n++)
#pragma unroll
            for (int r = 0; r < 4; r++) {
                int row = wr * 64 + m * 16 + (lane >> 4) * 4 + r;
                int col = hbase + wc * 64 + n * 16 + (lane & 15);
                float a = accg[m][n][r], u = accu[m][n][r];
                float hv = (a / (1.0f + expf(-a))) * u;
                hbuf[(slotbase + row) * HDIM + col] = (__bf16)hv;
            }
}

// ------- down GEMM: m97 structure, BK=64, 64x64 wave tiles + T2 swizzle -------
// (r11 verified config) Tile 128x128, K=1536 (24 steps unrolled). LDS 32 KB;
// 432 blocks at 3/CU: all co-resident, cross-block drain hiding active.
__global__ __launch_bounds__(256, 3) void down_kernel(
    const __bf16* __restrict__ hbuf, const __bf16* __restrict__ Dt,
    const int* __restrict__ ctrl, __bf16* __restrict__ ybuf)
{
    int bid = blockIdx.x;
    int swz = (bid & 7) * (MAXMB * 6 / 8) + (bid >> 3);   // 432 % 8 == 0
    int mb = swz / 6, y = swz - mb * 6;
    if (mb >= ctrl[24]) return;
    int e = ctrl[32 + mb];
    int dbase = y * 128;
    const __bf16* Dn = Dt + (size_t)e * DDIM * HDIM;   // [D][H]

    __shared__ __bf16 lds[2 * 8192];   // 32 KB: A | B

    int tid = threadIdx.x;
    int lane = tid & 63, w = tid >> 6;
    int wr = w >> 1, wc = w & 1;

    int lr = tid >> 3;
    int lc = ((tid & 7) ^ (lr & 7)) << 3;
    const __bf16* gA = hbuf + (size_t)(mb * MBLK + lr) * HDIM + lc;   // + j*32 rows
    const __bf16* gB = Dn + (size_t)(dbase + lr) * HDIM + lc;
    const size_t rstep = (size_t)32 * HDIM;

    f32x4 acc[4][4];
#pragma unroll
    for (int m = 0; m < 4; m++)
#pragma unroll
        for (int n = 0; n < 4; n++) acc[m][n] = (f32x4)0.0f;

#pragma unroll
    for (int kt = 0; kt < HDIM / 64; kt++) {
        const int kk = kt * 64;
#pragma unroll
        for (int j = 0; j < 4; j++)
            GLOAD16(gA + kk + j * rstep, &lds[j * 2048 + tid * 8]);
#pragma unroll
        for (int j = 0; j < 4; j++)
            GLOAD16(gB + kk + j * rstep, &lds[8192 + j * 2048 + tid * 8]);
        __syncthreads();

#pragma unroll
        for (int ks = 0; ks < 2; ks++) {
            int kb = ks * 32 + (lane >> 4) * 8;
            bf16x8 af[4], bd[4];
#pragma unroll
            for (int m = 0; m < 4; m++) {
                int row = wr * 64 + m * 16 + (lane & 15);
                af[m] = *reinterpret_cast<const bf16x8*>(
                    &lds[row * 64 + (kb ^ ((row & 7) << 3))]);
            }
#pragma unroll
            for (int n = 0; n < 4; n++) {
                int col = wc * 64 + n * 16 + (lane & 15);
                bd[n] = *reinterpret_cast<const bf16x8*>(
                    &lds[8192 + col * 64 + (kb ^ ((col & 7) << 3))]);
            }
#pragma unroll
            for (int n = 0; n < 4; n++)
#pragma unroll
                for (int m = 0; m < 4; m++)
                    acc[m][n] = MFMA_BF16(af[m], bd[n], acc[m][n], 0, 0, 0);
        }
        __syncthreads();
    }

#pragma unroll
    for (int m = 0; m < 4; m++)
#pragma unroll
        for (int n = 0; n < 4; n++)
#pragma unroll
            for (int r = 0; r < 4; r++) {
                int row = wr * 64 + m * 16 + (lane >> 4) * 4 + r;
                int col = dbase + wc * 64 + n * 16 + (lane & 15);
                ybuf[(size_t)(mb * MBLK + row) * DDIM + col] = (__bf16)acc[m][n][r];
            }
}

// combine: out[t] = w0*y[s0] + w1*y[s1] (bf16 y, f32 math); overwrites d_out.
__global__ __launch_bounds__(192) void combine_kernel(
    const __bf16* __restrict__ ybuf, const int* __restrict__ slot_of,
    const float* __restrict__ topk_w, float* __restrict__ out)
{
    int t = blockIdx.x;
    int q = threadIdx.x;
    int s0 = slot_of[2*t], s1 = slot_of[2*t+1];
    float w0 = topk_w[2*t], w1 = topk_w[2*t+1];
    bf16x4 y0 = reinterpret_cast<const bf16x4*>(ybuf + (size_t)s0 * DDIM)[q];
    bf16x4 y1 = reinterpret_cast<const bf16x4*>(ybuf + (size_t)s1 * DDIM)[q];
    f32x4 o;
#pragma unroll
    for (int r = 0; r < 4; r++) o[r] = w0 * (float)y0[r] + w1 * (float)y1[r];
    reinterpret_cast<f32x4*>(out + (size_t)t * DDIM)[q] = o;
}

// ---------------- launch ----------------
extern "C" void kernel_launch(void* const* d_in, const int* in_sizes, int n_in,
                              void* d_out, int out_size, void* d_ws, size_t ws_size,
                              hipStream_t stream)
{
    if (ws_size < WS_NEEDED) return;

    const float* x      = (const float*)d_in[0];
    const float* gate_w = (const float*)d_in[1];
    const float* gbank  = (const float*)d_in[2];
    const float* ubank  = (const float*)d_in[3];
    const float* dbank  = (const float*)d_in[4];
    float* out = (float*)d_out;

    char* ws = (char*)d_ws;
    __bf16* xb   = (__bf16*)(ws + XB_OFF);
    __bf16* Gt   = (__bf16*)(ws + GT_OFF);
    __bf16* Ut   = (__bf16*)(ws + UT_OFF);
    __bf16* ybuf = (__bf16*)(ws + YB_OFF);
    __bf16* Dt   = (__bf16*)(ws + DT_OFF);
    __bf16* hbuf = (__bf16*)(ws + HB_OFF);
    int*    tki  = (int*)(ws + TKI_OFF);
    float*  tkw  = (float*)(ws + TKW_OFF);
    int*    pt   = (int*)(ws + PT_OFF);
    int*    slot = (int*)(ws + SL_OFF);
    int*    ctrl = (int*)(ws + CTRL_OFF);

    prep_kernel<<<NGATE + NTTILE, 256, 0, stream>>>(
        x, gate_w, tki, tkw, xb, gbank, ubank, dbank, Gt, Ut, Dt);
    route_kernel<<<1, RTHREADS, 0, stream>>>(tki, ctrl, pt, slot);

    gateup_kernel<<<MAXMB * (HDIM / 128), 256, 0, stream>>>(xb, Gt, Ut, ctrl, pt, hbuf);
    down_kernel<<<MAXMB * (DDIM / 128), 256, 0, stream>>>(hbuf, Dt, ctrl, ybuf);
    combine_kernel<<<NTOK, 192, 0, stream>>>(ybuf, slot, tkw, out);
}